// Round 9
// baseline (951.398 us; speedup 1.0000x reference)
//
#include <hip/hip_runtime.h>
#include <math.h>

#define B_  8
#define L_  2500
#define D_  512
#define Y_  8921
#define LP  2560    // L padded
#define YP  8960    // Y padded to 140*64

// ws layout: fp16 X[B_][LP][D_]
//          | G fragment-major: [yt(140)][kk2(16)][mi(8)][lane(64)][8]
//            (G row pairs U (sub 0-7) / F (sub 8-15) per 16-row group)
// then fp32  denG[B_][YP] | numG[B_][YP]
#define WS_F16_HALVES  (B_ * LP * D_ + 2 * YP * D_)
#define ACC_FLOATS     (2 * B_ * YP)

typedef _Float16 f16x8 __attribute__((ext_vector_type(8)));
typedef float    f32x4 __attribute__((ext_vector_type(4)));

__device__ __forceinline__ void load_lds16(const _Float16* g, _Float16* l) {
  __builtin_amdgcn_global_load_lds(
      (const __attribute__((address_space(1))) unsigned int*)g,
      (__attribute__((address_space(3))) unsigned int*)l, 16, 0, 0);
}

__global__ void k_convert(const float* __restrict__ x,
                          const float* __restrict__ Uw,
                          const float* __restrict__ Fw,
                          _Float16* __restrict__ ws,
                          float* __restrict__ loss_slot) {
  if (blockIdx.x == 0 && threadIdx.x == 0) *loss_slot = 0.0f;
  const int NX = B_ * LP * (D_ / 8);   // 1310720 slots
  int idx = blockIdx.x * 256 + threadIdx.x;
  if (idx < ACC_FLOATS) ((float*)(ws + WS_F16_HALVES))[idx] = 0.0f;
  const float* src = nullptr;
  if (idx < NX) {
    int b  = idx / (LP * 64);
    int r  = idx - b * (LP * 64);
    int l  = r >> 6;
    int d8 = r & 63;
    if (l < L_) src = x + (((long)b * L_ + l) * D_ + d8 * 8);
  } else {
    // G fragment-major slot: [yt][kk2][mi][lane]
    int u    = idx - NX;
    int lane = u & 63;
    int mi   = (u >> 6) & 7;
    int kk2  = (u >> 9) & 15;
    int yt   = u >> 13;
    int grow = yt * 128 + mi * 16 + (lane & 15);   // global G row
    int sub  = grow & 15;
    int y    = (grow >> 4) * 8 + (sub & 7);
    int k8   = kk2 * 4 + (lane >> 4);              // 8-elem k granule
    if (y < Y_) src = (sub < 8 ? Uw : Fw) + (long)y * D_ + k8 * 8;
  }
  f16x8 o;
  if (src) {
    const float4* s4 = (const float4*)src;
    float4 a = s4[0], c = s4[1];
    o[0] = (_Float16)a.x; o[1] = (_Float16)a.y; o[2] = (_Float16)a.z; o[3] = (_Float16)a.w;
    o[4] = (_Float16)c.x; o[5] = (_Float16)c.y; o[6] = (_Float16)c.z; o[7] = (_Float16)c.w;
  } else {
    for (int i = 0; i < 8; ++i) o[i] = (_Float16)0.0f;
  }
  ((f16x8*)ws)[idx] = o;
}

// Round 9: THIRD WAVE PER SIMD. Round-8 (zero-LDS) refuted the "LDS chain"
// theory (884 µs): staging IS the latency hider. Corrected totals for round
// 7: MFMA 42% (CU-level) + LDS 29% + VALU 32% of wall — pipes serialized
// along each wave's chain, 2 waves/SIMD (256 regs: 128 VGPR + acc[4][8]=128
// AGPR) give no third context to fill gaps. This round halves the
// accumulator: wave tile 64G x 64l -> acc[4][4] = 64 AGPR, est. ~100 arch
// VGPR, total ~165 <= 170 -> 3 waves/SIMD (enforced via launch_bounds
// (128,3)). Block = 2 waves G-split (128G x 64l), 8 KB stage per K-step.
// Inner loop / swizzles / epilogue / atomic layout = round 7 verbatim with
// ni range halved. Cost accepted: au L2 traffic 2.9 -> 5.7 GB (L2 at 38%).
// Grid 8960 = yt(140) x lo(8 l-eighths of 320) x b(8); XCD swizzle b=bid&7.
__global__ __launch_bounds__(128, 3)
void k_attn(const _Float16* __restrict__ ws,
            float* __restrict__ accG) {
  __shared__ __align__(16) _Float16 XT[4096];   // 64 rows x 64 halves

  const int tid  = threadIdx.x;
  const int lane = tid & 63;
  const int wave = tid >> 6;           // 0..1
  const int wy = wave;                 // G-half (64 G rows = 32 y)
  const int bid = blockIdx.x;          // 0..8959
  const int b   = bid & 7;             // XCD id (dispatch: bid % 8)
  const int lo  = (bid >> 3) & 7;      // l eighth (320 cols)
  const int yt  = bid >> 6;            // 0..139 (64 labels each)

  const _Float16* Xg = ws + (long)b * LP * D_ + (long)lo * 320 * D_;
  // fragment-major G base for this yt block + this wave's row-half + lane
  const _Float16* Ga = ws + (long)B_ * LP * D_ + (long)yt * (128 * 512)
                          + (wy * 4) * 512 + lane * 8;

  // X staging: 8 segments of 1KB (8 rows x 64 halves); 4 per wave
  const int srow = lane >> 3;
  const int sg8  = ((lane & 7) ^ srow) * 8;
  const _Float16* xsrc[4];
  _Float16*       xdst[4];
  #pragma unroll
  for (int i = 0; i < 4; ++i) {
    int seg = wave * 4 + i;
    xsrc[i] = Xg + (long)(seg * 8 + srow) * D_ + sg8;   // + lt*64 rows later
    xdst[i] = XT + seg * 512;
  }

  // compute geometry
  const int xrow = lane & 15;
  const int r7   = lane & 7;
  const int gb   = lane >> 4;
  const bool sLow = (lane < 32);

  float redP[4][4];   // den partials (lanes 0-31) / num partials (lanes 32-63)
  #pragma unroll
  for (int i = 0; i < 4; ++i)
    for (int v = 0; v < 4; ++v) redP[i][v] = 0.0f;

  for (int lt = 0; lt < 5; ++lt) {
    f32x4 acc[4][4];
    #pragma unroll
    for (int mi = 0; mi < 4; ++mi)
      for (int ni = 0; ni < 4; ++ni) {
        f32x4 z = {0.0f, 0.0f, 0.0f, 0.0f};
        acc[mi][ni] = z;
      }
    const long xofs = (long)lt * 64 * D_;
    for (int kkstep = 0; kkstep < 8; ++kkstep) {
      // A-fragments direct from global (L2) — issued before the barriers so
      // their latency hides under the X stage + drain window
      f16x8 au[2][4];
      #pragma unroll
      for (int ks = 0; ks < 2; ++ks)
        #pragma unroll
        for (int mi = 0; mi < 4; ++mi)
          au[ks][mi] = *(const f16x8*)(Ga + (size_t)(kkstep * 2 + ks) * 4096 + mi * 512);
      __syncthreads();
      #pragma unroll
      for (int i = 0; i < 4; ++i)
        load_lds16(xsrc[i] + xofs + kkstep * 64, xdst[i]);
      __syncthreads();
      #pragma unroll
      for (int ks = 0; ks < 2; ++ks) {
        int off = (((ks * 4 + gb) ^ r7) * 8);
        f16x8 bx[4];
        #pragma unroll
        for (int ni = 0; ni < 4; ++ni)
          bx[ni] = *(const f16x8*)&XT[(xrow + ni * 16) * 64 + off];
        #pragma unroll
        for (int mi = 0; mi < 4; ++mi)
          #pragma unroll
          for (int ni = 0; ni < 4; ++ni)
            acc[mi][ni] = __builtin_amdgcn_mfma_f32_16x16x32_f16(au[ks][mi], bx[ni], acc[mi][ni], 0, 0, 0);
      }
    }
    // epilogue: low lanes hold S -> e=exp(S), den += e; shfl_xor(e,32) hands e
    // to the C half; upper lanes num += e * C. Pad cols: e=1 exact, C=0.
    #pragma unroll
    for (int mi = 0; mi < 4; ++mi)
      for (int ni = 0; ni < 4; ++ni)
        #pragma unroll
        for (int v = 0; v < 4; ++v) {
          float a = acc[mi][ni][v];
          float e = __expf(a);
          float p = __shfl_xor(e, 32, 64);
          redP[mi][v] += sLow ? e : p * a;
        }
  }

  // reduce over the 16 columns sharing each label row
  for (int m = 1; m < 16; m <<= 1)
    #pragma unroll
    for (int mi = 0; mi < 4; ++mi)
      for (int v = 0; v < 4; ++v)
        redP[mi][v] += __shfl_xor(redP[mi][v], m, 64);
  if ((lane & 15) == 0) {
    float* dst = accG + (sLow ? 0 : B_ * YP);   // den | num
    #pragma unroll
    for (int mi = 0; mi < 4; ++mi)
      for (int v = 0; v < 4; ++v) {
        int y = yt * 64 + wy * 32 + mi * 8 + ((lane >> 4) & 1) * 4 + v;
        atomicAdd(&dst[b * YP + y], redP[mi][v]);
      }
  }
}

__global__ void k_final(const float* __restrict__ accG,
                        const float* __restrict__ fb,
                        float* __restrict__ out) {
  int id = blockIdx.x * 256 + threadIdx.x;
  if (id >= B_ * Y_) return;
  int b = id / Y_, y = id - b * Y_;
  float den = accG[b * YP + y] - (float)(LP - L_);
  out[id] = accG[B_ * YP + b * YP + y] / den + fb[y];
}

__global__ void k_loss(const float* __restrict__ y,
                       const float* __restrict__ t,
                       float* __restrict__ loss) {
  float p = 0.0f;
  for (int i = blockIdx.x * 256 + threadIdx.x; i < B_ * Y_; i += gridDim.x * 256) {
    float v = y[i], tg = t[i];
    p += fmaxf(v, 0.0f) - v * tg + log1pf(__expf(-fabsf(v)));
  }
  for (int m = 32; m; m >>= 1) p += __shfl_down(p, m, 64);
  __shared__ float wsum[4];
  int lane = threadIdx.x & 63, wv = threadIdx.x >> 6;
  if (lane == 0) wsum[wv] = p;
  __syncthreads();
  if (threadIdx.x == 0) {
    float s = wsum[0] + wsum[1] + wsum[2] + wsum[3];
    atomicAdd(loss, s * (1.0f / (float)(B_ * Y_)));
  }
}

extern "C" void kernel_launch(void* const* d_in, const int* in_sizes, int n_in,
                              void* d_out, int out_size, void* d_ws, size_t ws_size,
                              hipStream_t stream) {
  (void)in_sizes; (void)n_in; (void)out_size; (void)ws_size;
  const float* x       = (const float*)d_in[0];
  const float* target  = (const float*)d_in[1];
  const float* U_w     = (const float*)d_in[3];
  const float* final_w = (const float*)d_in[4];
  const float* final_b = (const float*)d_in[5];
  float* out = (float*)d_out;
  _Float16* ws = (_Float16*)d_ws;
  float* accG = (float*)(ws + WS_F16_HALVES);

  k_convert<<<9600, 256, 0, stream>>>(x, U_w, final_w, ws, out + B_ * Y_);

  k_attn<<<8960, 128, 0, stream>>>(ws, accG);

  k_final<<<(B_ * Y_ + 255) / 256, 256, 0, stream>>>(accG, final_b, out);
  k_loss<<<140, 256, 0, stream>>>(out, target, out + B_ * Y_);
}

// Round 10
// 483.757 us; speedup vs baseline: 1.9667x; 1.9667x over previous
//
#include <hip/hip_runtime.h>
#include <math.h>

#define B_  8
#define L_  2500
#define D_  512
#define Y_  8921
#define LP  2560    // L padded
#define YP  8960    // Y padded to 140*64

// ws layout: fp16 X[B_][LP][D_]
//          | G fragment-major: [yt(140)][kk2(16)][mi(8)][lane(64)][8]
//            ROW-PARITY pairing: within each 16-row group, row 2k = U row of
//            y k, row 2k+1 = F row of y k  (changed from 0-7=U / 8-15=F)
// then fp32  denG[B_][YP] | numG[B_][YP]
#define WS_F16_HALVES  (B_ * LP * D_ + 2 * YP * D_)
#define ACC_FLOATS     (2 * B_ * YP)

typedef _Float16 f16x8 __attribute__((ext_vector_type(8)));
typedef float    f32x4 __attribute__((ext_vector_type(4)));

__device__ __forceinline__ void load_lds16(const _Float16* g, _Float16* l) {
  __builtin_amdgcn_global_load_lds(
      (const __attribute__((address_space(1))) unsigned int*)g,
      (__attribute__((address_space(3))) unsigned int*)l, 16, 0, 0);
}

__global__ void k_convert(const float* __restrict__ x,
                          const float* __restrict__ Uw,
                          const float* __restrict__ Fw,
                          _Float16* __restrict__ ws,
                          float* __restrict__ loss_slot) {
  if (blockIdx.x == 0 && threadIdx.x == 0) *loss_slot = 0.0f;
  const int NX = B_ * LP * (D_ / 8);   // 1310720 slots
  int idx = blockIdx.x * 256 + threadIdx.x;
  if (idx < ACC_FLOATS) ((float*)(ws + WS_F16_HALVES))[idx] = 0.0f;
  const float* src = nullptr;
  if (idx < NX) {
    int b  = idx / (LP * 64);
    int r  = idx - b * (LP * 64);
    int l  = r >> 6;
    int d8 = r & 63;
    if (l < L_) src = x + (((long)b * L_ + l) * D_ + d8 * 8);
  } else {
    // G fragment-major slot: [yt][kk2][mi][lane]
    int u    = idx - NX;
    int lane = u & 63;
    int mi   = (u >> 6) & 7;
    int kk2  = (u >> 9) & 15;
    int yt   = u >> 13;
    int grow = yt * 128 + mi * 16 + (lane & 15);   // global G row
    int sub  = grow & 15;
    int y    = (grow >> 4) * 8 + (sub >> 1);       // ROW-PARITY pairing
    int k8   = kk2 * 4 + (lane >> 4);              // 8-elem k granule
    if (y < Y_) src = (((sub & 1) == 0) ? Uw : Fw) + (long)y * D_ + k8 * 8;
  }
  f16x8 o;
  if (src) {
    const float4* s4 = (const float4*)src;
    float4 a = s4[0], c = s4[1];
    o[0] = (_Float16)a.x; o[1] = (_Float16)a.y; o[2] = (_Float16)a.z; o[3] = (_Float16)a.w;
    o[4] = (_Float16)c.x; o[5] = (_Float16)c.y; o[6] = (_Float16)c.z; o[7] = (_Float16)c.w;
  } else {
    for (int i = 0; i < 8; ++i) o[i] = (_Float16)0.0f;
  }
  ((f16x8*)ws)[idx] = o;
}

// Round 10: SAME-LANE U/F EPILOGUE on the round-7 base (best: 431 µs).
// Round-9 lesson recorded: occupancy bought by shrinking the tile destroys
// L2 footprint + per-sync intensity (FETCH 0.39->1.7 GB, 883 µs) — the
// 64Gx128l acc[4][8] tile stays. This round removes the epilogue's wasted
// work: with ROW-PARITY G pairing, the C/D tile rows (row=(lane>>4)*4+v)
// give each lane (S,C) of the SAME y in v-pairs (0,1) and (2,3):
//   e = expf(acc[v0]); den += e; num += e*acc[v1]
// -> zero shfl_xor(32) (was 128 ds_permute/lt/wave), zero cndmask, exp
// count halved to exactly the useful 128/tile-row. Pad cols still add
// (1,0) exactly (S=0,C=0 -> e=1). Everything else = round 7 verbatim.
__global__ __launch_bounds__(128, 2)
void k_attn(const _Float16* __restrict__ ws,
            float* __restrict__ accG) {
  __shared__ __align__(16) _Float16 XT[8192];   // 128 rows x 64 halves

  const int tid  = threadIdx.x;
  const int lane = tid & 63;
  const int wave = tid >> 6;           // 0..1
  const int wy = wave;                 // G-half (64 G rows = 32 y)
  const int bid = blockIdx.x;          // 0..4479
  const int b   = bid & 7;             // XCD id (dispatch: bid % 8)
  const int lq  = (bid >> 3) & 3;      // l quarter (640 cols)
  const int yt  = bid >> 5;            // 0..139 (64 labels each)

  const _Float16* Xg = ws + (long)b * LP * D_ + (long)lq * 640 * D_;
  // fragment-major G base for this yt block + this wave's row-half + lane
  const _Float16* Ga = ws + (long)B_ * LP * D_ + (long)yt * (128 * 512)
                          + (wy * 4) * 512 + lane * 8;

  // X staging: 16 segments of 1KB (8 rows x 64 halves); 8 per wave
  const int srow = lane >> 3;
  const int sg8  = ((lane & 7) ^ srow) * 8;
  const _Float16* xsrc[8];
  _Float16*       xdst[8];
  #pragma unroll
  for (int i = 0; i < 8; ++i) {
    int seg = wave * 8 + i;
    xsrc[i] = Xg + (long)(seg * 8 + srow) * D_ + sg8;   // + lt*128 rows later
    xdst[i] = XT + seg * 512;
  }

  // compute geometry
  const int xrow = lane & 15;
  const int r7   = lane & 7;
  const int gb   = lane >> 4;

  float redD[4][2], redN[4][2];  // den/num partials: y_local = 2*(lane>>4)+j
  #pragma unroll
  for (int i = 0; i < 4; ++i)
    for (int j = 0; j < 2; ++j) { redD[i][j] = 0.0f; redN[i][j] = 0.0f; }

  for (int lt = 0; lt < 5; ++lt) {
    f32x4 acc[4][8];
    #pragma unroll
    for (int mi = 0; mi < 4; ++mi)
      for (int ni = 0; ni < 8; ++ni) {
        f32x4 z = {0.0f, 0.0f, 0.0f, 0.0f};
        acc[mi][ni] = z;
      }
    const long xofs = (long)lt * 128 * D_;
    for (int kkstep = 0; kkstep < 8; ++kkstep) {
      // A-fragments direct from global (L2) — issued before the barriers so
      // their latency hides under the X stage + drain window
      f16x8 au[2][4];
      #pragma unroll
      for (int ks = 0; ks < 2; ++ks)
        #pragma unroll
        for (int mi = 0; mi < 4; ++mi)
          au[ks][mi] = *(const f16x8*)(Ga + (size_t)(kkstep * 2 + ks) * 4096 + mi * 512);
      __syncthreads();
      #pragma unroll
      for (int i = 0; i < 8; ++i)
        load_lds16(xsrc[i] + xofs + kkstep * 64, xdst[i]);
      __syncthreads();
      #pragma unroll
      for (int ks = 0; ks < 2; ++ks) {
        int off = (((ks * 4 + gb) ^ r7) * 8);
        f16x8 bx[8];
        #pragma unroll
        for (int ni = 0; ni < 8; ++ni)
          bx[ni] = *(const f16x8*)&XT[(xrow + ni * 16) * 64 + off];
        #pragma unroll
        for (int mi = 0; mi < 4; ++mi)
          #pragma unroll
          for (int ni = 0; ni < 8; ++ni)
            acc[mi][ni] = __builtin_amdgcn_mfma_f32_16x16x32_f16(au[ks][mi], bx[ni], acc[mi][ni], 0, 0, 0);
      }
    }
    // epilogue (same-lane): v0/v1 = (S,C) of y_local 2g; v2/v3 = of 2g+1.
    // Pad cols: S=0,C=0 -> e=1 exact, num += 0; k_final subtracts LP-L_.
    #pragma unroll
    for (int mi = 0; mi < 4; ++mi)
      #pragma unroll
      for (int ni = 0; ni < 8; ++ni) {
        float e0 = __expf(acc[mi][ni][0]);
        float e1 = __expf(acc[mi][ni][2]);
        redD[mi][0] += e0;
        redN[mi][0] += e0 * acc[mi][ni][1];
        redD[mi][1] += e1;
        redN[mi][1] += e1 * acc[mi][ni][3];
      }
  }

  // reduce over the 16 columns sharing each label row
  for (int m = 1; m < 16; m <<= 1)
    #pragma unroll
    for (int mi = 0; mi < 4; ++mi)
      for (int j = 0; j < 2; ++j) {
        redD[mi][j] += __shfl_xor(redD[mi][j], m, 64);
        redN[mi][j] += __shfl_xor(redN[mi][j], m, 64);
      }
  if ((lane & 15) == 0) {
    const int g = lane >> 4;
    #pragma unroll
    for (int mi = 0; mi < 4; ++mi)
      for (int j = 0; j < 2; ++j) {
        int y = yt * 64 + wy * 32 + mi * 8 + g * 2 + j;
        atomicAdd(&accG[b * YP + y], redD[mi][j]);
        atomicAdd(&accG[B_ * YP + b * YP + y], redN[mi][j]);
      }
  }
}

__global__ void k_final(const float* __restrict__ accG,
                        const float* __restrict__ fb,
                        float* __restrict__ out) {
  int id = blockIdx.x * 256 + threadIdx.x;
  if (id >= B_ * Y_) return;
  int b = id / Y_, y = id - b * Y_;
  float den = accG[b * YP + y] - (float)(LP - L_);
  out[id] = accG[B_ * YP + b * YP + y] / den + fb[y];
}

__global__ void k_loss(const float* __restrict__ y,
                       const float* __restrict__ t,
                       float* __restrict__ loss) {
  float p = 0.0f;
  for (int i = blockIdx.x * 256 + threadIdx.x; i < B_ * Y_; i += gridDim.x * 256) {
    float v = y[i], tg = t[i];
    p += fmaxf(v, 0.0f) - v * tg + log1pf(__expf(-fabsf(v)));
  }
  for (int m = 32; m; m >>= 1) p += __shfl_down(p, m, 64);
  __shared__ float wsum[4];
  int lane = threadIdx.x & 63, wv = threadIdx.x >> 6;
  if (lane == 0) wsum[wv] = p;
  __syncthreads();
  if (threadIdx.x == 0) {
    float s = wsum[0] + wsum[1] + wsum[2] + wsum[3];
    atomicAdd(loss, s * (1.0f / (float)(B_ * Y_)));
  }
}

extern "C" void kernel_launch(void* const* d_in, const int* in_sizes, int n_in,
                              void* d_out, int out_size, void* d_ws, size_t ws_size,
                              hipStream_t stream) {
  (void)in_sizes; (void)n_in; (void)out_size; (void)ws_size;
  const float* x       = (const float*)d_in[0];
  const float* target  = (const float*)d_in[1];
  const float* U_w     = (const float*)d_in[3];
  const float* final_w = (const float*)d_in[4];
  const float* final_b = (const float*)d_in[5];
  float* out = (float*)d_out;
  _Float16* ws = (_Float16*)d_ws;
  float* accG = (float*)(ws + WS_F16_HALVES);

  k_convert<<<9600, 256, 0, stream>>>(x, U_w, final_w, ws, out + B_ * Y_);

  k_attn<<<4480, 128, 0, stream>>>(ws, accG);

  k_final<<<(B_ * Y_ + 255) / 256, 256, 0, stream>>>(accG, final_b, out);
  k_loss<<<140, 256, 0, stream>>>(out, target, out + B_ * Y_);
}